// Round 3
// baseline (316.658 us; speedup 1.0000x reference)
//
#include <hip/hip_runtime.h>

// MoE top-2 SwiGLU: out[p] = (silu(x_t @ w13[e][:, :I]) * (x_t @ w13[e][:, I:])) @ w2[e]
// p = t*K + k, e = expert_indices[t][k]. Inputs/outputs are fp32 (per reference);
// internal compute uses fp16 MFMA (fp32 accumulate) — within the harness's
// bf16-floor tolerance (floor_eps_k=8 -> ~8.1e-3 absmax allowance).
// Structure: route -> transpose weights (fp32 -> fp16, k-contiguous) ->
//            gemm1(+silu, fp16 h_ws) -> gemm2(scatter fp32 out)

#define H_DIM 512
#define I_DIM 1024
#define E_NUM 8
#define TOPK 2
#define P_PAIRS 16384   // B*S*K = 4*2048*2
#define CAP P_PAIRS     // per-expert capacity (worst case all pairs in one expert)
#define LDA 40          // LDS row stride in halves: 80 B, 16B-aligned, 2-way bank alias (free)

typedef _Float16 half8 __attribute__((ext_vector_type(8)));
typedef float f32x4 __attribute__((ext_vector_type(4)));

// ---------------------------------------------------------------- routing ---
__global__ void route_k(const int* __restrict__ idx, int* __restrict__ counts,
                        int* __restrict__ lists) {
  const int p = blockIdx.x * blockDim.x + threadIdx.x;
  if (p < P_PAIRS) {
    const int e = idx[p];
    const int pos = atomicAdd(&counts[e], 1);
    lists[e * CAP + pos] = p;
  }
}

// ------------------------------------------- weight transpose + f32->fp16 ---
// in: fp32 [E][R][C] row-major; out: fp16 [E][C][R] (k-dim contiguous for MFMA frags)
__global__ __launch_bounds__(256) void transpose_cvt_k(
    const float* __restrict__ in, _Float16* __restrict__ out, int R, int C) {
  __shared__ _Float16 tile[32][33];
  const int e = blockIdx.z;
  const float* src = in + (size_t)e * R * C;
  _Float16* dst = out + (size_t)e * C * R;
  const int c0 = blockIdx.x * 32;
  const int r0 = blockIdx.y * 32;
  const int tc = threadIdx.x & 31;
  const int tr = threadIdx.x >> 5;  // 0..7
  for (int rr = 0; rr < 32; rr += 8)
    tile[tr + rr][tc] = (_Float16)src[(size_t)(r0 + tr + rr) * C + c0 + tc];
  __syncthreads();
  for (int rr = 0; rr < 32; rr += 8)
    dst[(size_t)(c0 + tr + rr) * R + r0 + tc] = tile[tc][tr + rr];
}

// ------------------------------------------------------------------ GEMM 1 ---
// Gathered rows of x (64 pairs of one expert) @ w13[e] -> silu(gate)*up -> h_ws (fp16).
// Block tile: M=64, N=64 gate cols (+ matching 64 up cols), K-step 32.
// 4 waves in 2x2; each wave: 2x2 mfma 16x16x32 tiles for gate AND up.
__global__ __launch_bounds__(256) void gemm1_k(
    const float* __restrict__ x, const _Float16* __restrict__ w13t,
    const int* __restrict__ counts, const int* __restrict__ lists,
    _Float16* __restrict__ h_ws) {
  const int e = blockIdx.z;
  const int ne = counts[e];
  const int m0 = blockIdx.y * 64;
  if (m0 >= ne) return;
  const int ng0 = blockIdx.x * 64;  // gate column base in [0, I)

  __shared__ int rows[64];
  __shared__ __align__(16) _Float16 As[64 * LDA];
  __shared__ __align__(16) _Float16 Bgs[64 * LDA];  // transposed: [n][k]
  __shared__ __align__(16) _Float16 Bus[64 * LDA];

  const int tid = threadIdx.x;
  if (tid < 64) {
    const int m = m0 + tid;
    rows[tid] = (m < ne) ? lists[e * CAP + m] : -1;
  }
  __syncthreads();

  const int lane = tid & 63;
  const int wid = tid >> 6;
  const int wm = wid & 1;
  const int wn = wid >> 1;
  const int fm = lane & 15;
  const int q = lane >> 4;

  // staging: thread -> (row sr, 8-col segment sc)
  const int sr = tid >> 2;
  const int sc = (tid & 3) * 8;
  const int p_r = rows[sr];
  const float* xrow = (p_r >= 0) ? (x + (size_t)(p_r >> 1) * H_DIM) : nullptr;  // t = p/K
  const _Float16* wg = w13t + ((size_t)e * (2 * I_DIM) + (ng0 + sr)) * H_DIM;
  const _Float16* wu = wg + (size_t)I_DIM * H_DIM;

  f32x4 accg[2][2] = {};
  f32x4 accu[2][2] = {};

  for (int k0 = 0; k0 < H_DIM; k0 += 32) {
    half8 av = {0, 0, 0, 0, 0, 0, 0, 0};
    if (xrow) {
      f32x4 v0 = *(const f32x4*)(xrow + k0 + sc);
      f32x4 v1 = *(const f32x4*)(xrow + k0 + sc + 4);
      for (int j = 0; j < 4; ++j) { av[j] = (_Float16)v0[j]; av[j + 4] = (_Float16)v1[j]; }
    }
    *(half8*)&As[sr * LDA + sc] = av;
    *(half8*)&Bgs[sr * LDA + sc] = *(const half8*)(wg + k0 + sc);
    *(half8*)&Bus[sr * LDA + sc] = *(const half8*)(wu + k0 + sc);
    __syncthreads();

    half8 afr[2], bgf[2], buf2[2];
    for (int mi = 0; mi < 2; ++mi)
      afr[mi] = *(const half8*)&As[(wm * 32 + mi * 16 + fm) * LDA + q * 8];
    for (int ni = 0; ni < 2; ++ni) {
      bgf[ni] = *(const half8*)&Bgs[(wn * 32 + ni * 16 + fm) * LDA + q * 8];
      buf2[ni] = *(const half8*)&Bus[(wn * 32 + ni * 16 + fm) * LDA + q * 8];
    }
    for (int mi = 0; mi < 2; ++mi)
      for (int ni = 0; ni < 2; ++ni) {
        accg[mi][ni] = __builtin_amdgcn_mfma_f32_16x16x32_f16(afr[mi], bgf[ni], accg[mi][ni], 0, 0, 0);
        accu[mi][ni] = __builtin_amdgcn_mfma_f32_16x16x32_f16(afr[mi], buf2[ni], accu[mi][ni], 0, 0, 0);
      }
    __syncthreads();
  }

  // epilogue: C/D layout col=lane&15, row=q*4+reg  (HW-verified, dtype-independent)
  for (int mi = 0; mi < 2; ++mi)
    for (int r = 0; r < 4; ++r) {
      const int mrow = wm * 32 + mi * 16 + q * 4 + r;
      const int p = rows[mrow];
      if (p < 0) continue;
      _Float16* hrow = h_ws + (size_t)p * I_DIM + ng0;
      for (int ni = 0; ni < 2; ++ni) {
        const int nc = wn * 32 + ni * 16 + fm;
        const float g = accg[mi][ni][r];
        const float u = accu[mi][ni][r];
        const float s = g / (1.0f + __expf(-g));  // silu
        hrow[nc] = (_Float16)(s * u);
      }
    }
}

// ------------------------------------------------------------------ GEMM 2 ---
// h_ws rows (gathered) @ w2[e] -> scatter fp32 to out rows p.
__global__ __launch_bounds__(256) void gemm2_k(
    const _Float16* __restrict__ h_ws, const _Float16* __restrict__ w2t,
    const int* __restrict__ counts, const int* __restrict__ lists,
    float* __restrict__ out) {
  const int e = blockIdx.z;
  const int ne = counts[e];
  const int m0 = blockIdx.y * 64;
  if (m0 >= ne) return;
  const int n0 = blockIdx.x * 64;  // h column base in [0, H)

  __shared__ int rows[64];
  __shared__ __align__(16) _Float16 As[64 * LDA];
  __shared__ __align__(16) _Float16 Bs[64 * LDA];

  const int tid = threadIdx.x;
  if (tid < 64) {
    const int m = m0 + tid;
    rows[tid] = (m < ne) ? lists[e * CAP + m] : -1;
  }
  __syncthreads();

  const int lane = tid & 63;
  const int wid = tid >> 6;
  const int wm = wid & 1;
  const int wn = wid >> 1;
  const int fm = lane & 15;
  const int q = lane >> 4;

  const int sr = tid >> 2;
  const int sc = (tid & 3) * 8;
  const int p_r = rows[sr];
  const _Float16* arow = (p_r >= 0) ? (h_ws + (size_t)p_r * I_DIM) : nullptr;
  const _Float16* brow = w2t + ((size_t)e * H_DIM + (n0 + sr)) * I_DIM;

  f32x4 acc[2][2] = {};

  for (int k0 = 0; k0 < I_DIM; k0 += 32) {
    half8 av = {0, 0, 0, 0, 0, 0, 0, 0};
    if (arow) av = *(const half8*)(arow + k0 + sc);
    *(half8*)&As[sr * LDA + sc] = av;
    *(half8*)&Bs[sr * LDA + sc] = *(const half8*)(brow + k0 + sc);
    __syncthreads();

    half8 afr[2], bfr[2];
    for (int mi = 0; mi < 2; ++mi)
      afr[mi] = *(const half8*)&As[(wm * 32 + mi * 16 + fm) * LDA + q * 8];
    for (int ni = 0; ni < 2; ++ni)
      bfr[ni] = *(const half8*)&Bs[(wn * 32 + ni * 16 + fm) * LDA + q * 8];
    for (int mi = 0; mi < 2; ++mi)
      for (int ni = 0; ni < 2; ++ni)
        acc[mi][ni] = __builtin_amdgcn_mfma_f32_16x16x32_f16(afr[mi], bfr[ni], acc[mi][ni], 0, 0, 0);
    __syncthreads();
  }

  for (int mi = 0; mi < 2; ++mi)
    for (int r = 0; r < 4; ++r) {
      const int mrow = wm * 32 + mi * 16 + q * 4 + r;
      const int p = rows[mrow];
      if (p < 0) continue;
      float* orow = out + (size_t)p * H_DIM + n0;
      for (int ni = 0; ni < 2; ++ni) {
        const int nc = wn * 32 + ni * 16 + fm;
        orow[nc] = acc[mi][ni][r];
      }
    }
}

// ------------------------------------------------------------------ launch ---
extern "C" void kernel_launch(void* const* d_in, const int* in_sizes, int n_in,
                              void* d_out, int out_size, void* d_ws, size_t ws_size,
                              hipStream_t stream) {
  const float* x = (const float*)d_in[0];    // fp32 (B,S,H)
  const int* idx = (const int*)d_in[1];      // int32 (B,S,K)
  const float* w13 = (const float*)d_in[2];  // fp32 (E,H,2I)
  const float* w2 = (const float*)d_in[3];   // fp32 (E,I,H)

  char* ws = (char*)d_ws;
  int* counts = (int*)ws;                                        // 32 B (pad 256)
  int* lists = (int*)(ws + 256);                                 // 512 KB
  const size_t OFF_W13T = 256 + (size_t)E_NUM * CAP * 4;         // 524544
  const size_t OFF_W2T = OFF_W13T + (size_t)E_NUM * 2 * I_DIM * H_DIM * 2;  // +16.78 MB
  const size_t OFF_H = OFF_W2T + (size_t)E_NUM * H_DIM * I_DIM * 2;         // +8.39 MB
  _Float16* w13t = (_Float16*)(ws + OFF_W13T);  // [E][2I][H] fp16
  _Float16* w2t = (_Float16*)(ws + OFF_W2T);    // [E][H][I]  fp16
  _Float16* h_ws = (_Float16*)(ws + OFF_H);     // [P][I]     fp16 (33.5 MB)

  hipMemsetAsync(d_ws, 0, 256, stream);  // zero expert counts
  route_k<<<dim3(P_PAIRS / 256), 256, 0, stream>>>(idx, counts, lists);
  transpose_cvt_k<<<dim3(2 * I_DIM / 32, H_DIM / 32, E_NUM), 256, 0, stream>>>(
      w13, w13t, H_DIM, 2 * I_DIM);
  transpose_cvt_k<<<dim3(H_DIM / 32, I_DIM / 32, E_NUM), 256, 0, stream>>>(
      w2, w2t, I_DIM, H_DIM);
  gemm1_k<<<dim3(I_DIM / 64, CAP / 64, E_NUM), 256, 0, stream>>>(
      x, w13t, counts, lists, h_ws);
  gemm2_k<<<dim3(H_DIM / 64, CAP / 64, E_NUM), 256, 0, stream>>>(
      h_ws, w2t, counts, lists, (float*)d_out);
}

// Round 4
// 279.626 us; speedup vs baseline: 1.1324x; 1.1324x over previous
//
#include <hip/hip_runtime.h>

// MoE top-2 SwiGLU (fp32 in/out, fp16 MFMA internal).
// route -> cvt x->fp16 -> transpose w13,w2 (fp32->fp16, k-contiguous) ->
// gemm1 (128x64 tile: gate+up, silu fused, global_load_lds staging) ->
// gemm2 (128x128 tile, scatter fp32 out).
// LDS tiles are unpadded (global_load_lds needs lane-order contiguity); bank
// conflicts killed by XOR seg swizzle applied on the GLOBAL address side.

#define H_DIM 512
#define I_DIM 1024
#define E_NUM 8
#define P_PAIRS 16384
#define CAP P_PAIRS

typedef _Float16 half8 __attribute__((ext_vector_type(8)));
typedef float f32x4 __attribute__((ext_vector_type(4)));
typedef unsigned int u32;
typedef const __attribute__((address_space(1))) u32* gas_t;
typedef __attribute__((address_space(3))) u32* las_t;

__device__ __forceinline__ void glds16(const void* g, void* l) {
  __builtin_amdgcn_global_load_lds((gas_t)g, (las_t)l, 16, 0, 0);
}

// ---------------------------------------------------------------- routing ---
__global__ void route_k(const int* __restrict__ idx, int* __restrict__ counts,
                        int* __restrict__ lists) {
  const int p = blockIdx.x * blockDim.x + threadIdx.x;
  if (p < P_PAIRS) {
    const int e = idx[p];
    const int pos = atomicAdd(&counts[e], 1);
    lists[e * CAP + pos] = p;
  }
}

// ------------------------------------------------------------- x -> fp16 ---
__global__ __launch_bounds__(256) void cvt_x_k(const float* __restrict__ x,
                                               _Float16* __restrict__ xh) {
  const size_t i = ((size_t)blockIdx.x * 256 + threadIdx.x) * 8;
  f32x4 v0 = *(const f32x4*)(x + i);
  f32x4 v1 = *(const f32x4*)(x + i + 4);
  half8 h;
  for (int j = 0; j < 4; ++j) { h[j] = (_Float16)v0[j]; h[j + 4] = (_Float16)v1[j]; }
  *(half8*)(xh + i) = h;
}

// ------------------------------------------- weight transpose + f32->fp16 ---
// in: fp32 [E][R][C]; out: fp16 [E][C][R]. 64x64 tiles, coalesced both sides.
__global__ __launch_bounds__(256) void transpose_cvt_k(
    const float* __restrict__ in, _Float16* __restrict__ out, int R, int C) {
  __shared__ _Float16 tile[64][72];
  const int e = blockIdx.z;
  const float* src = in + (size_t)e * R * C;
  _Float16* dst = out + (size_t)e * C * R;
  const int c0 = blockIdx.x * 64;
  const int r0 = blockIdx.y * 64;
  const int tid = threadIdx.x;
  {
    const int r = tid >> 4;          // 0..15
    const int c4 = (tid & 15) * 4;   // 0..60
    for (int pass = 0; pass < 4; ++pass) {
      f32x4 v = *(const f32x4*)(src + (size_t)(r0 + pass * 16 + r) * C + c0 + c4);
      for (int j = 0; j < 4; ++j) tile[c4 + j][pass * 16 + r] = (_Float16)v[j];
    }
  }
  __syncthreads();
  {
    const int c = tid >> 3;          // 0..31
    const int r8 = (tid & 7) * 8;    // 0..56
    for (int pass = 0; pass < 2; ++pass) {
      half8 h = *(const half8*)&tile[pass * 32 + c][r8];
      *(half8*)(dst + (size_t)(c0 + pass * 32 + c) * R + r0 + r8) = h;
    }
  }
}

// ------------------------------------------------------------------ GEMM 1 ---
// Block: M=128 gathered pairs, 64 gate cols + 64 up cols, K=512, BK=32.
// 4 waves 2x2: wave = 64 rows x (32g + 32u). global_load_lds staging, XOR swizzle.
__global__ __launch_bounds__(256) void gemm1_k(
    const _Float16* __restrict__ xh, const _Float16* __restrict__ w13t,
    const int* __restrict__ counts, const int* __restrict__ lists,
    _Float16* __restrict__ h_ws) {
  const int e = blockIdx.z;
  const int ne = counts[e];
  const int m0 = blockIdx.y * 128;
  if (m0 >= ne) return;
  const int n0 = blockIdx.x * 64;

  __shared__ int rows[128];
  __shared__ __align__(16) _Float16 As[128 * 32];   // 8 KB
  __shared__ __align__(16) _Float16 Bgs[64 * 32];   // 4 KB
  __shared__ __align__(16) _Float16 Bus[64 * 32];   // 4 KB

  const int tid = threadIdx.x;
  if (tid < 128) {
    const int m = m0 + tid;
    rows[tid] = (m < ne) ? lists[e * CAP + m] : -1;
  }
  __syncthreads();

  // ---- staging descriptors: row r = tid/4, seg s = tid%4 (16B each) ----
  const int sr = tid >> 2;
  const int s4 = tid & 3;
  const int segoff = ((s4 ^ ((sr >> 1) & 3)) * 8);  // XOR swizzle, period-8 rows
  const int pa0 = rows[sr];
  const int pa1 = rows[64 + sr];
  const int t0 = (pa0 >= 0) ? (pa0 >> 1) : 0;
  const int t1 = (pa1 >= 0) ? (pa1 >> 1) : 0;
  const _Float16* ga0 = xh + (size_t)t0 * H_DIM + segoff;
  const _Float16* ga1 = xh + (size_t)t1 * H_DIM + segoff;
  const _Float16* gbg = w13t + ((size_t)e * 2 * I_DIM + n0 + sr) * H_DIM + segoff;
  const _Float16* gbu = gbg + (size_t)I_DIM * H_DIM;
  _Float16* la0 = As + sr * 32 + s4 * 8;
  _Float16* la1 = As + (64 + sr) * 32 + s4 * 8;
  _Float16* lbg = Bgs + sr * 32 + s4 * 8;
  _Float16* lbu = Bus + sr * 32 + s4 * 8;

  // ---- fragment descriptors ----
  const int lane = tid & 63;
  const int wid = tid >> 6;
  const int wm = wid & 1;
  const int wn = wid >> 1;
  const int fm = lane & 15;
  const int q = lane >> 4;
  int aoff[4], boff[2];
  for (int mi = 0; mi < 4; ++mi) {
    const int rA = wm * 64 + mi * 16 + fm;
    aoff[mi] = rA * 32 + ((q ^ ((rA >> 1) & 3)) * 8);
  }
  for (int ni = 0; ni < 2; ++ni) {
    const int cB = wn * 32 + ni * 16 + fm;
    boff[ni] = cB * 32 + ((q ^ ((cB >> 1) & 3)) * 8);
  }

  f32x4 accg[4][2] = {};
  f32x4 accu[4][2] = {};

  for (int k0 = 0; k0 < H_DIM; k0 += 32) {
    glds16(ga0 + k0, la0);
    glds16(ga1 + k0, la1);
    glds16(gbg + k0, lbg);
    glds16(gbu + k0, lbu);
    __syncthreads();

    half8 af[4], bg[2], bu[2];
    for (int mi = 0; mi < 4; ++mi) af[mi] = *(const half8*)&As[aoff[mi]];
    for (int ni = 0; ni < 2; ++ni) {
      bg[ni] = *(const half8*)&Bgs[boff[ni]];
      bu[ni] = *(const half8*)&Bus[boff[ni]];
    }
    for (int mi = 0; mi < 4; ++mi)
      for (int ni = 0; ni < 2; ++ni) {
        accg[mi][ni] = __builtin_amdgcn_mfma_f32_16x16x32_f16(af[mi], bg[ni], accg[mi][ni], 0, 0, 0);
        accu[mi][ni] = __builtin_amdgcn_mfma_f32_16x16x32_f16(af[mi], bu[ni], accu[mi][ni], 0, 0, 0);
      }
    __syncthreads();
  }

  // epilogue: C/D layout col=lane&15, row=q*4+reg; silu(g)*u -> fp16 h_ws
  for (int mi = 0; mi < 4; ++mi)
    for (int r = 0; r < 4; ++r) {
      const int mrow = wm * 64 + mi * 16 + q * 4 + r;
      const int p = rows[mrow];
      if (p < 0) continue;
      _Float16* hrow = h_ws + (size_t)p * I_DIM + n0;
      for (int ni = 0; ni < 2; ++ni) {
        const int c = wn * 32 + ni * 16 + fm;
        const float g = accg[mi][ni][r];
        const float u = accu[mi][ni][r];
        hrow[c] = (_Float16)(g / (1.0f + __expf(-g)) * u);
      }
    }
}

// ------------------------------------------------------------------ GEMM 2 ---
// Block: M=128 gathered pairs x N=128 out cols, K=1024, BK=32. 4 waves 2x2,
// wave = 64x64 (4x4 mfma tiles). Scatter fp32 rows to out.
__global__ __launch_bounds__(256) void gemm2_k(
    const _Float16* __restrict__ h_ws, const _Float16* __restrict__ w2t,
    const int* __restrict__ counts, const int* __restrict__ lists,
    float* __restrict__ out) {
  const int e = blockIdx.z;
  const int ne = counts[e];
  const int m0 = blockIdx.y * 128;
  if (m0 >= ne) return;
  const int n0 = blockIdx.x * 128;

  __shared__ int rows[128];
  __shared__ __align__(16) _Float16 As[128 * 32];  // 8 KB
  __shared__ __align__(16) _Float16 Bs[128 * 32];  // 8 KB

  const int tid = threadIdx.x;
  if (tid < 128) {
    const int m = m0 + tid;
    rows[tid] = (m < ne) ? lists[e * CAP + m] : -1;
  }
  __syncthreads();

  const int sr = tid >> 2;
  const int s4 = tid & 3;
  const int segoff = ((s4 ^ ((sr >> 1) & 3)) * 8);
  const int pa0 = rows[sr];
  const int pa1 = rows[64 + sr];
  const _Float16* ga0 = h_ws + (size_t)((pa0 >= 0) ? pa0 : 0) * I_DIM + segoff;
  const _Float16* ga1 = h_ws + (size_t)((pa1 >= 0) ? pa1 : 0) * I_DIM + segoff;
  const _Float16* gb0 = w2t + ((size_t)e * H_DIM + n0 + sr) * I_DIM + segoff;
  const _Float16* gb1 = gb0 + (size_t)64 * I_DIM;
  _Float16* la0 = As + sr * 32 + s4 * 8;
  _Float16* la1 = As + (64 + sr) * 32 + s4 * 8;
  _Float16* lb0 = Bs + sr * 32 + s4 * 8;
  _Float16* lb1 = Bs + (64 + sr) * 32 + s4 * 8;

  const int lane = tid & 63;
  const int wid = tid >> 6;
  const int wm = wid & 1;
  const int wn = wid >> 1;
  const int fm = lane & 15;
  const int q = lane >> 4;
  int aoff[4], boff[4];
  for (int mi = 0; mi < 4; ++mi) {
    const int rA = wm * 64 + mi * 16 + fm;
    aoff[mi] = rA * 32 + ((q ^ ((rA >> 1) & 3)) * 8);
  }
  for (int ni = 0; ni < 4; ++ni) {
    const int cB = wn * 64 + ni * 16 + fm;
    boff[ni] = cB * 32 + ((q ^ ((cB >> 1) & 3)) * 8);
  }

  f32x4 acc[4][4] = {};

  for (int k0 = 0; k0 < I_DIM; k0 += 32) {
    glds16(ga0 + k0, la0);
    glds16(ga1 + k0, la1);
    glds16(gb0 + k0, lb0);
    glds16(gb1 + k0, lb1);
    __syncthreads();

    half8 af[4], bf[4];
    for (int mi = 0; mi < 4; ++mi) af[mi] = *(const half8*)&As[aoff[mi]];
    for (int ni = 0; ni < 4; ++ni) bf[ni] = *(const half8*)&Bs[boff[ni]];
    for (int mi = 0; mi < 4; ++mi)
      for (int ni = 0; ni < 4; ++ni)
        acc[mi][ni] = __builtin_amdgcn_mfma_f32_16x16x32_f16(af[mi], bf[ni], acc[mi][ni], 0, 0, 0);
    __syncthreads();
  }

  for (int mi = 0; mi < 4; ++mi)
    for (int r = 0; r < 4; ++r) {
      const int mrow = wm * 64 + mi * 16 + q * 4 + r;
      const int p = rows[mrow];
      if (p < 0) continue;
      float* orow = out + (size_t)p * H_DIM + n0;
      for (int ni = 0; ni < 4; ++ni)
        orow[wn * 64 + ni * 16 + fm] = acc[mi][ni][r];
    }
}

// ------------------------------------------------------------------ launch ---
extern "C" void kernel_launch(void* const* d_in, const int* in_sizes, int n_in,
                              void* d_out, int out_size, void* d_ws, size_t ws_size,
                              hipStream_t stream) {
  const float* x = (const float*)d_in[0];
  const int* idx = (const int*)d_in[1];
  const float* w13 = (const float*)d_in[2];
  const float* w2 = (const float*)d_in[3];

  char* ws = (char*)d_ws;
  int* counts = (int*)ws;                               // 256 B
  int* lists = (int*)(ws + 256);                        // 512 KB
  const size_t OFF_XH = 256 + (size_t)E_NUM * CAP * 4;                      // 524544
  const size_t OFF_W13T = OFF_XH + (size_t)P_PAIRS / 2 * H_DIM * 2;         // +8.39 MB
  const size_t OFF_W2T = OFF_W13T + (size_t)E_NUM * 2 * I_DIM * H_DIM * 2;  // +16.78 MB
  const size_t OFF_H = OFF_W2T + (size_t)E_NUM * H_DIM * I_DIM * 2;         // +8.39 MB
  _Float16* xh = (_Float16*)(ws + OFF_XH);     // [B*S][H] fp16
  _Float16* w13t = (_Float16*)(ws + OFF_W13T); // [E][2I][H] fp16
  _Float16* w2t = (_Float16*)(ws + OFF_W2T);   // [E][H][I]  fp16
  _Float16* h_ws = (_Float16*)(ws + OFF_H);    // [P][I]     fp16 (33.5 MB)

  hipMemsetAsync(d_ws, 0, 256, stream);
  route_k<<<dim3(P_PAIRS / 256), 256, 0, stream>>>(idx, counts, lists);
  cvt_x_k<<<dim3((P_PAIRS / 2) * H_DIM / (256 * 8)), 256, 0, stream>>>(x, xh);
  transpose_cvt_k<<<dim3(2 * I_DIM / 64, H_DIM / 64, E_NUM), 256, 0, stream>>>(
      w13, w13t, H_DIM, 2 * I_DIM);
  transpose_cvt_k<<<dim3(H_DIM / 64, I_DIM / 64, E_NUM), 256, 0, stream>>>(
      w2, w2t, I_DIM, H_DIM);
  gemm1_k<<<dim3(I_DIM / 64, CAP / 128, E_NUM), 256, 0, stream>>>(
      xh, w13t, counts, lists, h_ws);
  gemm2_k<<<dim3(H_DIM / 128, CAP / 128, E_NUM), 256, 0, stream>>>(
      h_ws, w2t, counts, lists, (float*)d_out);
}

// Round 5
// 226.070 us; speedup vs baseline: 1.4007x; 1.2369x over previous
//
#include <hip/hip_runtime.h>

// MoE top-2 SwiGLU (fp32 in/out, fp16 MFMA internal).
// route (LDS-hist, low-contention) -> tiles (compact (e,m0) list) ->
// cvt x->fp16 -> transpose w13,w2 (fp32->fp16, k-contiguous) ->
// gemm1 (128x64 tile: gate+up, silu fused, global_load_lds staging) ->
// gemm2 (128x128 tile, scatter fp32 out).
// LDS tiles unpadded (global_load_lds is wave-uniform-base + lane*16); bank
// conflicts killed by XOR seg swizzle applied on the GLOBAL address side.

#define H_DIM 512
#define I_DIM 1024
#define E_NUM 8
#define P_PAIRS 16384
#define CAP P_PAIRS
#define MAX_TILES 136   // sum ceil(ne/128) <= 16384/128 + 7 = 135

typedef _Float16 half8 __attribute__((ext_vector_type(8)));
typedef float f32x4 __attribute__((ext_vector_type(4)));
typedef unsigned int u32;
typedef const __attribute__((address_space(1))) u32* gas_t;
typedef __attribute__((address_space(3))) u32* las_t;

__device__ __forceinline__ void glds16(const void* g, void* l) {
  __builtin_amdgcn_global_load_lds((gas_t)g, (las_t)l, 16, 0, 0);
}

// ---------------------------------------------------------------- routing ---
// Per-block LDS histogram -> 8 global atomics/block (512 total, was 16384).
__global__ __launch_bounds__(256) void route_k(const int* __restrict__ idx,
                                               int* __restrict__ counts,
                                               int* __restrict__ lists) {
  __shared__ int lcnt[E_NUM];
  __shared__ int lbase[E_NUM];
  const int tid = threadIdx.x;
  if (tid < E_NUM) lcnt[tid] = 0;
  __syncthreads();
  const int p = blockIdx.x * 256 + tid;
  const int e = idx[p];
  const int r = atomicAdd(&lcnt[e], 1);  // LDS atomic: rank within block
  __syncthreads();
  if (tid < E_NUM) lbase[tid] = atomicAdd(&counts[tid], lcnt[tid]);
  __syncthreads();
  lists[e * CAP + lbase[e] + r] = p;
}

// -------------------------------------------------- compact (e,m0) tile list
__global__ void tiles_k(const int* __restrict__ counts, int* __restrict__ tiles,
                        int* __restrict__ n_tiles) {
  if (threadIdx.x == 0) {
    int t = 0;
    for (int e = 0; e < E_NUM; ++e) {
      const int ne = counts[e];
      for (int m0 = 0; m0 < ne; m0 += 128) tiles[t++] = (e << 16) | m0;
    }
    n_tiles[0] = t;
  }
}

// ------------------------------------------------------------- x -> fp16 ---
__global__ __launch_bounds__(256) void cvt_x_k(const float* __restrict__ x,
                                               _Float16* __restrict__ xh) {
  const size_t i = ((size_t)blockIdx.x * 256 + threadIdx.x) * 8;
  f32x4 v0 = *(const f32x4*)(x + i);
  f32x4 v1 = *(const f32x4*)(x + i + 4);
  half8 h;
  for (int j = 0; j < 4; ++j) { h[j] = (_Float16)v0[j]; h[j + 4] = (_Float16)v1[j]; }
  *(half8*)(xh + i) = h;
}

// ------------------------------------------- weight transpose + f32->fp16 ---
// in: fp32 [E][R][C]; out: fp16 [E][C][R]. 64x64 tiles, coalesced both sides.
__global__ __launch_bounds__(256) void transpose_cvt_k(
    const float* __restrict__ in, _Float16* __restrict__ out, int R, int C) {
  __shared__ _Float16 tile[64][72];
  const int e = blockIdx.z;
  const float* src = in + (size_t)e * R * C;
  _Float16* dst = out + (size_t)e * C * R;
  const int c0 = blockIdx.x * 64;
  const int r0 = blockIdx.y * 64;
  const int tid = threadIdx.x;
  {
    const int r = tid >> 4;          // 0..15
    const int c4 = (tid & 15) * 4;   // 0..60
    for (int pass = 0; pass < 4; ++pass) {
      f32x4 v = *(const f32x4*)(src + (size_t)(r0 + pass * 16 + r) * C + c0 + c4);
      for (int j = 0; j < 4; ++j) tile[c4 + j][pass * 16 + r] = (_Float16)v[j];
    }
  }
  __syncthreads();
  {
    const int c = tid >> 3;          // 0..31
    const int r8 = (tid & 7) * 8;    // 0..56
    for (int pass = 0; pass < 2; ++pass) {
      half8 h = *(const half8*)&tile[pass * 32 + c][r8];
      *(half8*)(dst + (size_t)(c0 + pass * 32 + c) * R + r0 + r8) = h;
    }
  }
}

// ------------------------------------------------------------------ GEMM 1 ---
// Tile from list: 128 gathered pairs x (64 gate + 64 up cols), K=512, BK=32.
__global__ __launch_bounds__(256) void gemm1_k(
    const _Float16* __restrict__ xh, const _Float16* __restrict__ w13t,
    const int* __restrict__ tiles, const int* __restrict__ n_tiles,
    const int* __restrict__ counts, const int* __restrict__ lists,
    _Float16* __restrict__ h_ws) {
  const int ty = blockIdx.y;
  if (ty >= n_tiles[0]) return;
  const int tinfo = tiles[ty];
  const int e = tinfo >> 16;
  const int m0 = tinfo & 0xffff;
  const int ne = counts[e];
  const int n0 = blockIdx.x * 64;

  __shared__ int rows[128];
  __shared__ __align__(16) _Float16 As[128 * 32];   // 8 KB
  __shared__ __align__(16) _Float16 Bgs[64 * 32];   // 4 KB
  __shared__ __align__(16) _Float16 Bus[64 * 32];   // 4 KB

  const int tid = threadIdx.x;
  if (tid < 128) {
    const int m = m0 + tid;
    rows[tid] = (m < ne) ? lists[e * CAP + m] : -1;
  }
  __syncthreads();

  // ---- staging: row sr = tid/4, seg s4 = tid%4 (16B), XOR swizzle on global side
  const int sr = tid >> 2;
  const int s4 = tid & 3;
  const int segoff = ((s4 ^ ((sr >> 1) & 3)) * 8);
  const int pa0 = rows[sr];
  const int pa1 = rows[64 + sr];
  const int t0 = (pa0 >= 0) ? (pa0 >> 1) : 0;
  const int t1 = (pa1 >= 0) ? (pa1 >> 1) : 0;
  const _Float16* ga0 = xh + (size_t)t0 * H_DIM + segoff;
  const _Float16* ga1 = xh + (size_t)t1 * H_DIM + segoff;
  const _Float16* gbg = w13t + ((size_t)e * 2 * I_DIM + n0 + sr) * H_DIM + segoff;
  const _Float16* gbu = gbg + (size_t)I_DIM * H_DIM;
  _Float16* la0 = As + sr * 32 + s4 * 8;
  _Float16* la1 = As + (64 + sr) * 32 + s4 * 8;
  _Float16* lbg = Bgs + sr * 32 + s4 * 8;
  _Float16* lbu = Bus + sr * 32 + s4 * 8;

  const int lane = tid & 63;
  const int wid = tid >> 6;
  const int wm = wid & 1;
  const int wn = wid >> 1;
  const int fm = lane & 15;
  const int q = lane >> 4;
  int aoff[4], boff[2];
  for (int mi = 0; mi < 4; ++mi) {
    const int rA = wm * 64 + mi * 16 + fm;
    aoff[mi] = rA * 32 + ((q ^ ((rA >> 1) & 3)) * 8);
  }
  for (int ni = 0; ni < 2; ++ni) {
    const int cB = wn * 32 + ni * 16 + fm;
    boff[ni] = cB * 32 + ((q ^ ((cB >> 1) & 3)) * 8);
  }

  f32x4 accg[4][2] = {};
  f32x4 accu[4][2] = {};

  for (int k0 = 0; k0 < H_DIM; k0 += 32) {
    glds16(ga0 + k0, la0);
    glds16(ga1 + k0, la1);
    glds16(gbg + k0, lbg);
    glds16(gbu + k0, lbu);
    __syncthreads();

    half8 af[4], bg[2], bu[2];
    for (int mi = 0; mi < 4; ++mi) af[mi] = *(const half8*)&As[aoff[mi]];
    for (int ni = 0; ni < 2; ++ni) {
      bg[ni] = *(const half8*)&Bgs[boff[ni]];
      bu[ni] = *(const half8*)&Bus[boff[ni]];
    }
    for (int mi = 0; mi < 4; ++mi)
      for (int ni = 0; ni < 2; ++ni) {
        accg[mi][ni] = __builtin_amdgcn_mfma_f32_16x16x32_f16(af[mi], bg[ni], accg[mi][ni], 0, 0, 0);
        accu[mi][ni] = __builtin_amdgcn_mfma_f32_16x16x32_f16(af[mi], bu[ni], accu[mi][ni], 0, 0, 0);
      }
    __syncthreads();
  }

  // epilogue: C/D layout col=lane&15, row=q*4+reg; silu(g)*u -> fp16 h_ws
  for (int mi = 0; mi < 4; ++mi)
    for (int r = 0; r < 4; ++r) {
      const int mrow = wm * 64 + mi * 16 + q * 4 + r;
      const int p = rows[mrow];
      if (p < 0) continue;
      _Float16* hrow = h_ws + (size_t)p * I_DIM + n0;
      for (int ni = 0; ni < 2; ++ni) {
        const int c = wn * 32 + ni * 16 + fm;
        const float g = accg[mi][ni][r];
        const float u = accu[mi][ni][r];
        hrow[c] = (_Float16)(g / (1.0f + __expf(-g)) * u);
      }
    }
}

// ------------------------------------------------------------------ GEMM 2 ---
// Tile from list: 128 gathered pairs x N=128 out cols, K=1024, BK=32.
__global__ __launch_bounds__(256) void gemm2_k(
    const _Float16* __restrict__ h_ws, const _Float16* __restrict__ w2t,
    const int* __restrict__ tiles, const int* __restrict__ n_tiles,
    const int* __restrict__ counts, const int* __restrict__ lists,
    float* __restrict__ out) {
  const int ty = blockIdx.y;
  if (ty >= n_tiles[0]) return;
  const int tinfo = tiles[ty];
  const int e = tinfo >> 16;
  const int m0 = tinfo & 0xffff;
  const int ne = counts[e];
  const int n0 = blockIdx.x * 128;

  __shared__ int rows[128];
  __shared__ __align__(16) _Float16 As[128 * 32];  // 8 KB
  __shared__ __align__(16) _Float16 Bs[128 * 32];  // 8 KB

  const int tid = threadIdx.x;
  if (tid < 128) {
    const int m = m0 + tid;
    rows[tid] = (m < ne) ? lists[e * CAP + m] : -1;
  }
  __syncthreads();

  const int sr = tid >> 2;
  const int s4 = tid & 3;
  const int segoff = ((s4 ^ ((sr >> 1) & 3)) * 8);
  const int pa0 = rows[sr];
  const int pa1 = rows[64 + sr];
  const _Float16* ga0 = h_ws + (size_t)((pa0 >= 0) ? pa0 : 0) * I_DIM + segoff;
  const _Float16* ga1 = h_ws + (size_t)((pa1 >= 0) ? pa1 : 0) * I_DIM + segoff;
  const _Float16* gb0 = w2t + ((size_t)e * H_DIM + n0 + sr) * I_DIM + segoff;
  const _Float16* gb1 = gb0 + (size_t)64 * I_DIM;
  _Float16* la0 = As + sr * 32 + s4 * 8;
  _Float16* la1 = As + (64 + sr) * 32 + s4 * 8;
  _Float16* lb0 = Bs + sr * 32 + s4 * 8;
  _Float16* lb1 = Bs + (64 + sr) * 32 + s4 * 8;

  const int lane = tid & 63;
  const int wid = tid >> 6;
  const int wm = wid & 1;
  const int wn = wid >> 1;
  const int fm = lane & 15;
  const int q = lane >> 4;
  int aoff[4], boff[4];
  for (int mi = 0; mi < 4; ++mi) {
    const int rA = wm * 64 + mi * 16 + fm;
    aoff[mi] = rA * 32 + ((q ^ ((rA >> 1) & 3)) * 8);
  }
  for (int ni = 0; ni < 4; ++ni) {
    const int cB = wn * 64 + ni * 16 + fm;
    boff[ni] = cB * 32 + ((q ^ ((cB >> 1) & 3)) * 8);
  }

  f32x4 acc[4][4] = {};

  for (int k0 = 0; k0 < I_DIM; k0 += 32) {
    glds16(ga0 + k0, la0);
    glds16(ga1 + k0, la1);
    glds16(gb0 + k0, lb0);
    glds16(gb1 + k0, lb1);
    __syncthreads();

    half8 af[4], bf[4];
    for (int mi = 0; mi < 4; ++mi) af[mi] = *(const half8*)&As[aoff[mi]];
    for (int ni = 0; ni < 4; ++ni) bf[ni] = *(const half8*)&Bs[boff[ni]];
    for (int mi = 0; mi < 4; ++mi)
      for (int ni = 0; ni < 4; ++ni)
        acc[mi][ni] = __builtin_amdgcn_mfma_f32_16x16x32_f16(af[mi], bf[ni], acc[mi][ni], 0, 0, 0);
    __syncthreads();
  }

  for (int mi = 0; mi < 4; ++mi)
    for (int r = 0; r < 4; ++r) {
      const int mrow = wm * 64 + mi * 16 + q * 4 + r;
      const int p = rows[mrow];
      if (p < 0) continue;
      float* orow = out + (size_t)p * H_DIM + n0;
      for (int ni = 0; ni < 4; ++ni)
        orow[wn * 64 + ni * 16 + fm] = acc[mi][ni][r];
    }
}

// ------------------------------------------------------------------ launch ---
extern "C" void kernel_launch(void* const* d_in, const int* in_sizes, int n_in,
                              void* d_out, int out_size, void* d_ws, size_t ws_size,
                              hipStream_t stream) {
  const float* x = (const float*)d_in[0];
  const int* idx = (const int*)d_in[1];
  const float* w13 = (const float*)d_in[2];
  const float* w2 = (const float*)d_in[3];

  char* ws = (char*)d_ws;
  int* counts = (int*)ws;                  // 8 ints (pad to 128)
  int* n_tiles = (int*)(ws + 128);         // 1 int
  int* tiles = (int*)(ws + 256);           // MAX_TILES ints (pad to 2048)
  int* lists = (int*)(ws + 2048);          // 512 KB
  const size_t OFF_XH = 2048 + (size_t)E_NUM * CAP * 4;
  const size_t OFF_W13T = OFF_XH + (size_t)P_PAIRS / 2 * H_DIM * 2;          // +8.39 MB
  const size_t OFF_W2T = OFF_W13T + (size_t)E_NUM * 2 * I_DIM * H_DIM * 2;   // +16.78 MB
  const size_t OFF_H = OFF_W2T + (size_t)E_NUM * H_DIM * I_DIM * 2;          // +8.39 MB
  _Float16* xh = (_Float16*)(ws + OFF_XH);     // [B*S][H] fp16
  _Float16* w13t = (_Float16*)(ws + OFF_W13T); // [E][2I][H] fp16
  _Float16* w2t = (_Float16*)(ws + OFF_W2T);   // [E][H][I]  fp16
  _Float16* h_ws = (_Float16*)(ws + OFF_H);    // [P][I]     fp16 (33.5 MB)

  hipMemsetAsync(d_ws, 0, 128, stream);  // zero expert counts
  route_k<<<dim3(P_PAIRS / 256), 256, 0, stream>>>(idx, counts, lists);
  tiles_k<<<dim3(1), 64, 0, stream>>>(counts, tiles, n_tiles);
  cvt_x_k<<<dim3((P_PAIRS / 2) * H_DIM / (256 * 8)), 256, 0, stream>>>(x, xh);
  transpose_cvt_k<<<dim3(2 * I_DIM / 64, H_DIM / 64, E_NUM), 256, 0, stream>>>(
      w13, w13t, H_DIM, 2 * I_DIM);
  transpose_cvt_k<<<dim3(H_DIM / 64, I_DIM / 64, E_NUM), 256, 0, stream>>>(
      w2, w2t, I_DIM, H_DIM);
  gemm1_k<<<dim3(I_DIM / 64, MAX_TILES), 256, 0, stream>>>(
      xh, w13t, tiles, n_tiles, counts, lists, h_ws);
  gemm2_k<<<dim3(H_DIM / 128, MAX_TILES), 256, 0, stream>>>(
      h_ws, w2t, tiles, n_tiles, counts, lists, (float*)d_out);
}

// Round 6
// 224.207 us; speedup vs baseline: 1.4123x; 1.0083x over previous
//
#include <hip/hip_runtime.h>

// MoE top-2 SwiGLU (fp32 in/out, fp16 MFMA internal).
// route (LDS-hist) -> tiles (compact (e,m0) list) -> cvt x->fp16 ->
// transpose w13,w2 (fp32->fp16, k-contiguous) ->
// gemm1 (128x(64g+64u) tile, BK=64, silu fused, global_load_lds staging) ->
// gemm2 (128x128 tile, BK=64, scatter fp32 out).
// LDS tiles unpadded (global_load_lds is wave-uniform-base + lane*16); bank
// conflicts killed by XOR seg swizzle (8 segs/row) applied on the GLOBAL side.

#define H_DIM 512
#define I_DIM 1024
#define E_NUM 8
#define P_PAIRS 16384
#define CAP P_PAIRS
#define MAX_TILES 136   // sum ceil(ne/128) <= 16384/128 + 7 = 135

typedef _Float16 half8 __attribute__((ext_vector_type(8)));
typedef float f32x4 __attribute__((ext_vector_type(4)));
typedef unsigned int u32;
typedef const __attribute__((address_space(1))) u32* gas_t;
typedef __attribute__((address_space(3))) u32* las_t;

__device__ __forceinline__ void glds16(const void* g, void* l) {
  __builtin_amdgcn_global_load_lds((gas_t)g, (las_t)l, 16, 0, 0);
}

// ---------------------------------------------------------------- routing ---
__global__ __launch_bounds__(256) void route_k(const int* __restrict__ idx,
                                               int* __restrict__ counts,
                                               int* __restrict__ lists) {
  __shared__ int lcnt[E_NUM];
  __shared__ int lbase[E_NUM];
  const int tid = threadIdx.x;
  if (tid < E_NUM) lcnt[tid] = 0;
  __syncthreads();
  const int p = blockIdx.x * 256 + tid;
  const int e = idx[p];
  const int r = atomicAdd(&lcnt[e], 1);
  __syncthreads();
  if (tid < E_NUM) lbase[tid] = atomicAdd(&counts[tid], lcnt[tid]);
  __syncthreads();
  lists[e * CAP + lbase[e] + r] = p;
}

// -------------------------------------------------- compact (e,m0) tile list
__global__ void tiles_k(const int* __restrict__ counts, int* __restrict__ tiles,
                        int* __restrict__ n_tiles) {
  if (threadIdx.x == 0) {
    int t = 0;
    for (int e = 0; e < E_NUM; ++e) {
      const int ne = counts[e];
      for (int m0 = 0; m0 < ne; m0 += 128) tiles[t++] = (e << 16) | m0;
    }
    n_tiles[0] = t;
  }
}

// ------------------------------------------------------------- x -> fp16 ---
__global__ __launch_bounds__(256) void cvt_x_k(const float* __restrict__ x,
                                               _Float16* __restrict__ xh) {
  const size_t i = ((size_t)blockIdx.x * 256 + threadIdx.x) * 8;
  f32x4 v0 = *(const f32x4*)(x + i);
  f32x4 v1 = *(const f32x4*)(x + i + 4);
  half8 h;
  for (int j = 0; j < 4; ++j) { h[j] = (_Float16)v0[j]; h[j + 4] = (_Float16)v1[j]; }
  *(half8*)(xh + i) = h;
}

// ------------------------------------------- weight transpose + f32->fp16 ---
__global__ __launch_bounds__(256) void transpose_cvt_k(
    const float* __restrict__ in, _Float16* __restrict__ out, int R, int C) {
  __shared__ _Float16 tile[64][72];
  const int e = blockIdx.z;
  const float* src = in + (size_t)e * R * C;
  _Float16* dst = out + (size_t)e * C * R;
  const int c0 = blockIdx.x * 64;
  const int r0 = blockIdx.y * 64;
  const int tid = threadIdx.x;
  {
    const int r = tid >> 4;
    const int c4 = (tid & 15) * 4;
    for (int pass = 0; pass < 4; ++pass) {
      f32x4 v = *(const f32x4*)(src + (size_t)(r0 + pass * 16 + r) * C + c0 + c4);
      for (int j = 0; j < 4; ++j) tile[c4 + j][pass * 16 + r] = (_Float16)v[j];
    }
  }
  __syncthreads();
  {
    const int c = tid >> 3;
    const int r8 = (tid & 7) * 8;
    for (int pass = 0; pass < 2; ++pass) {
      half8 h = *(const half8*)&tile[pass * 32 + c][r8];
      *(half8*)(dst + (size_t)(c0 + pass * 32 + c) * R + r0 + r8) = h;
    }
  }
}

// ------------------------------------------------------------------ GEMM 1 ---
// Tile: 128 gathered pairs x (64 gate + 64 up cols), K=512, BK=64 (2 MFMA
// k-substeps per barrier pair). 4 waves 2x2.
__global__ __launch_bounds__(256) void gemm1_k(
    const _Float16* __restrict__ xh, const _Float16* __restrict__ w13t,
    const int* __restrict__ tiles, const int* __restrict__ n_tiles,
    const int* __restrict__ counts, const int* __restrict__ lists,
    _Float16* __restrict__ h_ws) {
  const int ty = blockIdx.y;
  if (ty >= n_tiles[0]) return;
  const int tinfo = tiles[ty];
  const int e = tinfo >> 16;
  const int m0 = tinfo & 0xffff;
  const int ne = counts[e];
  const int n0 = blockIdx.x * 64;

  __shared__ int rows[128];
  __shared__ __align__(16) _Float16 As[128 * 64];   // 16 KB
  __shared__ __align__(16) _Float16 Bgs[64 * 64];   // 8 KB
  __shared__ __align__(16) _Float16 Bus[64 * 64];   // 8 KB

  const int tid = threadIdx.x;
  if (tid < 128) {
    const int m = m0 + tid;
    rows[tid] = (m < ne) ? lists[e * CAP + m] : -1;
  }
  __syncthreads();

  // ---- staging: seg s8 = tid&7 (16B), row sr8 = tid>>3 (0..31), XOR swizzle
  const int s8 = tid & 7;
  const int sr8 = tid >> 3;
  const int sw = ((s8 ^ (sr8 & 7)) * 8);  // pass strides are multiples of 8 rows
  const _Float16* gA[4];
  _Float16* lA[4];
  for (int pa = 0; pa < 4; ++pa) {
    const int m = pa * 32 + sr8;
    const int p = rows[m];
    const int t = (p >= 0) ? (p >> 1) : 0;
    gA[pa] = xh + (size_t)t * H_DIM + sw;
    lA[pa] = As + m * 64 + s8 * 8;
  }
  const _Float16* gBg[2];
  const _Float16* gBu[2];
  _Float16* lBg[2];
  _Float16* lBu[2];
  for (int pb = 0; pb < 2; ++pb) {
    const int n = pb * 32 + sr8;
    gBg[pb] = w13t + ((size_t)e * 2 * I_DIM + n0 + n) * H_DIM + sw;
    gBu[pb] = gBg[pb] + (size_t)I_DIM * H_DIM;
    lBg[pb] = Bgs + n * 64 + s8 * 8;
    lBu[pb] = Bus + n * 64 + s8 * 8;
  }

  // ---- fragment offsets: logical seg (ks*4+q) -> physical ^ (row&7)
  const int lane = tid & 63;
  const int wid = tid >> 6;
  const int wm = wid & 1;
  const int wn = wid >> 1;
  const int fm = lane & 15;
  const int q = lane >> 4;
  int aoff[2][4], boff[2][2];
  for (int ks = 0; ks < 2; ++ks) {
    for (int mi = 0; mi < 4; ++mi) {
      const int rA = wm * 64 + mi * 16 + fm;
      aoff[ks][mi] = rA * 64 + (((ks * 4 + q) ^ (rA & 7)) * 8);
    }
    for (int ni = 0; ni < 2; ++ni) {
      const int cB = wn * 32 + ni * 16 + fm;
      boff[ks][ni] = cB * 64 + (((ks * 4 + q) ^ (cB & 7)) * 8);
    }
  }

  f32x4 accg[4][2] = {};
  f32x4 accu[4][2] = {};

  for (int k0 = 0; k0 < H_DIM; k0 += 64) {
    for (int pa = 0; pa < 4; ++pa) glds16(gA[pa] + k0, lA[pa]);
    for (int pb = 0; pb < 2; ++pb) {
      glds16(gBg[pb] + k0, lBg[pb]);
      glds16(gBu[pb] + k0, lBu[pb]);
    }
    __syncthreads();

    for (int ks = 0; ks < 2; ++ks) {
      half8 af[4], bg[2], bu[2];
      for (int mi = 0; mi < 4; ++mi) af[mi] = *(const half8*)&As[aoff[ks][mi]];
      for (int ni = 0; ni < 2; ++ni) {
        bg[ni] = *(const half8*)&Bgs[boff[ks][ni]];
        bu[ni] = *(const half8*)&Bus[boff[ks][ni]];
      }
      for (int mi = 0; mi < 4; ++mi)
        for (int ni = 0; ni < 2; ++ni) {
          accg[mi][ni] = __builtin_amdgcn_mfma_f32_16x16x32_f16(af[mi], bg[ni], accg[mi][ni], 0, 0, 0);
          accu[mi][ni] = __builtin_amdgcn_mfma_f32_16x16x32_f16(af[mi], bu[ni], accu[mi][ni], 0, 0, 0);
        }
    }
    __syncthreads();
  }

  // epilogue: C/D layout col=lane&15, row=q*4+reg; silu(g)*u -> fp16 h_ws
  for (int mi = 0; mi < 4; ++mi)
    for (int r = 0; r < 4; ++r) {
      const int mrow = wm * 64 + mi * 16 + q * 4 + r;
      const int p = rows[mrow];
      if (p < 0) continue;
      _Float16* hrow = h_ws + (size_t)p * I_DIM + n0;
      for (int ni = 0; ni < 2; ++ni) {
        const int c = wn * 32 + ni * 16 + fm;
        const float g = accg[mi][ni][r];
        const float u = accu[mi][ni][r];
        hrow[c] = (_Float16)(g / (1.0f + __expf(-g)) * u);
      }
    }
}

// ------------------------------------------------------------------ GEMM 2 ---
// Tile: 128 gathered pairs x 128 out cols, K=1024, BK=64. 4 waves 2x2.
__global__ __launch_bounds__(256) void gemm2_k(
    const _Float16* __restrict__ h_ws, const _Float16* __restrict__ w2t,
    const int* __restrict__ tiles, const int* __restrict__ n_tiles,
    const int* __restrict__ counts, const int* __restrict__ lists,
    float* __restrict__ out) {
  const int ty = blockIdx.y;
  if (ty >= n_tiles[0]) return;
  const int tinfo = tiles[ty];
  const int e = tinfo >> 16;
  const int m0 = tinfo & 0xffff;
  const int ne = counts[e];
  const int n0 = blockIdx.x * 128;

  __shared__ int rows[128];
  __shared__ __align__(16) _Float16 As[128 * 64];  // 16 KB
  __shared__ __align__(16) _Float16 Bs[128 * 64];  // 16 KB

  const int tid = threadIdx.x;
  if (tid < 128) {
    const int m = m0 + tid;
    rows[tid] = (m < ne) ? lists[e * CAP + m] : -1;
  }
  __syncthreads();

  const int s8 = tid & 7;
  const int sr8 = tid >> 3;
  const int sw = ((s8 ^ (sr8 & 7)) * 8);
  const _Float16* gA[4];
  const _Float16* gB[4];
  _Float16* lA[4];
  _Float16* lB[4];
  for (int pa = 0; pa < 4; ++pa) {
    const int m = pa * 32 + sr8;
    const int p = rows[m];
    gA[pa] = h_ws + (size_t)((p >= 0) ? p : 0) * I_DIM + sw;
    lA[pa] = As + m * 64 + s8 * 8;
    const int n = pa * 32 + sr8;
    gB[pa] = w2t + ((size_t)e * H_DIM + n0 + n) * I_DIM + sw;
    lB[pa] = Bs + n * 64 + s8 * 8;
  }

  const int lane = tid & 63;
  const int wid = tid >> 6;
  const int wm = wid & 1;
  const int wn = wid >> 1;
  const int fm = lane & 15;
  const int q = lane >> 4;
  int aoff[2][4], boff[2][4];
  for (int ks = 0; ks < 2; ++ks) {
    for (int mi = 0; mi < 4; ++mi) {
      const int rA = wm * 64 + mi * 16 + fm;
      aoff[ks][mi] = rA * 64 + (((ks * 4 + q) ^ (rA & 7)) * 8);
    }
    for (int ni = 0; ni < 4; ++ni) {
      const int cB = wn * 64 + ni * 16 + fm;
      boff[ks][ni] = cB * 64 + (((ks * 4 + q) ^ (cB & 7)) * 8);
    }
  }

  f32x4 acc[4][4] = {};

  for (int k0 = 0; k0 < I_DIM; k0 += 64) {
    for (int pa = 0; pa < 4; ++pa) {
      glds16(gA[pa] + k0, lA[pa]);
      glds16(gB[pa] + k0, lB[pa]);
    }
    __syncthreads();

    for (int ks = 0; ks < 2; ++ks) {
      half8 af[4], bf[4];
      for (int mi = 0; mi < 4; ++mi) af[mi] = *(const half8*)&As[aoff[ks][mi]];
      for (int ni = 0; ni < 4; ++ni) bf[ni] = *(const half8*)&Bs[boff[ks][ni]];
      for (int mi = 0; mi < 4; ++mi)
        for (int ni = 0; ni < 4; ++ni)
          acc[mi][ni] = __builtin_amdgcn_mfma_f32_16x16x32_f16(af[mi], bf[ni], acc[mi][ni], 0, 0, 0);
    }
    __syncthreads();
  }

  for (int mi = 0; mi < 4; ++mi)
    for (int r = 0; r < 4; ++r) {
      const int mrow = wm * 64 + mi * 16 + q * 4 + r;
      const int p = rows[mrow];
      if (p < 0) continue;
      float* orow = out + (size_t)p * H_DIM + n0;
      for (int ni = 0; ni < 4; ++ni)
        orow[wn * 64 + ni * 16 + fm] = acc[mi][ni][r];
    }
}

// ------------------------------------------------------------------ launch ---
extern "C" void kernel_launch(void* const* d_in, const int* in_sizes, int n_in,
                              void* d_out, int out_size, void* d_ws, size_t ws_size,
                              hipStream_t stream) {
  const float* x = (const float*)d_in[0];
  const int* idx = (const int*)d_in[1];
  const float* w13 = (const float*)d_in[2];
  const float* w2 = (const float*)d_in[3];

  char* ws = (char*)d_ws;
  int* counts = (int*)ws;                  // 8 ints (pad to 128)
  int* n_tiles = (int*)(ws + 128);         // 1 int
  int* tiles = (int*)(ws + 256);           // MAX_TILES ints (pad to 2048)
  int* lists = (int*)(ws + 2048);          // 512 KB
  const size_t OFF_XH = 2048 + (size_t)E_NUM * CAP * 4;
  const size_t OFF_W13T = OFF_XH + (size_t)P_PAIRS / 2 * H_DIM * 2;          // +8.39 MB
  const size_t OFF_W2T = OFF_W13T + (size_t)E_NUM * 2 * I_DIM * H_DIM * 2;   // +16.78 MB
  const size_t OFF_H = OFF_W2T + (size_t)E_NUM * H_DIM * I_DIM * 2;          // +8.39 MB
  _Float16* xh = (_Float16*)(ws + OFF_XH);     // [B*S][H] fp16
  _Float16* w13t = (_Float16*)(ws + OFF_W13T); // [E][2I][H] fp16
  _Float16* w2t = (_Float16*)(ws + OFF_W2T);   // [E][H][I]  fp16
  _Float16* h_ws = (_Float16*)(ws + OFF_H);    // [P][I]     fp16 (33.5 MB)

  hipMemsetAsync(d_ws, 0, 128, stream);  // zero expert counts
  route_k<<<dim3(P_PAIRS / 256), 256, 0, stream>>>(idx, counts, lists);
  tiles_k<<<dim3(1), 64, 0, stream>>>(counts, tiles, n_tiles);
  cvt_x_k<<<dim3((P_PAIRS / 2) * H_DIM / (256 * 8)), 256, 0, stream>>>(x, xh);
  transpose_cvt_k<<<dim3(2 * I_DIM / 64, H_DIM / 64, E_NUM), 256, 0, stream>>>(
      w13, w13t, H_DIM, 2 * I_DIM);
  transpose_cvt_k<<<dim3(H_DIM / 64, I_DIM / 64, E_NUM), 256, 0, stream>>>(
      w2, w2t, I_DIM, H_DIM);
  gemm1_k<<<dim3(I_DIM / 64, MAX_TILES), 256, 0, stream>>>(
      xh, w13t, tiles, n_tiles, counts, lists, h_ws);
  gemm2_k<<<dim3(H_DIM / 128, MAX_TILES), 256, 0, stream>>>(
      h_ws, w2t, tiles, n_tiles, counts, lists, (float*)d_out);
}